// Round 2
// baseline (867.124 us; speedup 1.0000x reference)
//
#include <hip/hip_runtime.h>

#define N_NODES 100000
#define N_EDGES 800000
#define D 128

typedef unsigned int u32;

// ---------------------------------------------------------------------------
// Precompute M = lin_w.T @ weight (f32) and b2 = lin_b @ weight (f32).
// grid = 129 blocks x 128 threads; block 128 handles b2.
// ---------------------------------------------------------------------------
__global__ __launch_bounds__(128) void precompute_kernel(
    const float* __restrict__ lin_w, const float* __restrict__ lin_b,
    const float* __restrict__ weight, float* __restrict__ M, float* __restrict__ b2)
{
    int j = threadIdx.x;
    int i = blockIdx.x;
    if (i < D) {
        float acc = 0.f;
        for (int o = 0; o < D; ++o)
            acc += lin_w[o * D + i] * weight[o * D + j];
        M[i * D + j] = acc;
    } else {
        float acc = 0.f;
        for (int o = 0; o < D; ++o)
            acc += lin_b[o] * weight[o * D + j];
        b2[j] = acc;
    }
}

// ---------------------------------------------------------------------------
// Edge scatter: one wave (64 lanes) per edge. Lane l handles features 2l,2l+1.
// agg (f32) += x[col]; deg[row] += 1.
// ---------------------------------------------------------------------------
__global__ __launch_bounds__(256) void scatter_kernel(
    const float* __restrict__ x, const int* __restrict__ ei,
    float* __restrict__ agg, u32* __restrict__ deg)
{
    int wave = (int)((blockIdx.x * blockDim.x + threadIdx.x) >> 6);
    int lane = threadIdx.x & 63;
    if (wave >= N_EDGES) return;
    int row = ei[wave];             // destination (segment id)
    int col = ei[N_EDGES + wave];   // source (gathered)

    float2 v = *(const float2*)(x + (size_t)col * D + lane * 2);

    float* dst = agg + (size_t)row * D + lane * 2;
    unsafeAtomicAdd(dst + 0, v.x);
    unsafeAtomicAdd(dst + 1, v.y);
    if (lane == 0) atomicAdd(deg + row, 1u);
}

// ---------------------------------------------------------------------------
// out[n,:] = (agg[n,:] / max(deg[n],1)) @ M + b2.
// 128 threads/block (thread = output column), ROWS rows per block.
// 1/deg scaling commutes with the GEMM row-sum; applied at epilogue.
// ---------------------------------------------------------------------------
#define ROWS 8
__global__ __launch_bounds__(128) void gemm_kernel(
    const float* __restrict__ agg, const u32* __restrict__ deg,
    const float* __restrict__ M, const float* __restrict__ b2,
    float* __restrict__ out)
{
    __shared__ float a_sh[ROWS][D];
    __shared__ float invdeg_sh[ROWS];
    int t = threadIdx.x;
    int n0 = blockIdx.x * ROWS;

    if (t < ROWS) {
        u32 d = deg[n0 + t];
        if (d < 1u) d = 1u;
        invdeg_sh[t] = 1.0f / (float)d;
    }
    #pragma unroll
    for (int r = 0; r < ROWS; ++r)
        a_sh[r][t] = agg[(size_t)(n0 + r) * D + t];
    __syncthreads();

    float acc[ROWS];
    #pragma unroll
    for (int r = 0; r < ROWS; ++r) acc[r] = 0.f;

    for (int i = 0; i < D; i += 4) {
        float m0 = M[(i + 0) * D + t];
        float m1 = M[(i + 1) * D + t];
        float m2 = M[(i + 2) * D + t];
        float m3 = M[(i + 3) * D + t];
        #pragma unroll
        for (int r = 0; r < ROWS; ++r) {
            float4 av = *(const float4*)&a_sh[r][i];
            acc[r] += av.x * m0 + av.y * m1 + av.z * m2 + av.w * m3;
        }
    }

    float bias = b2[t];
    #pragma unroll
    for (int r = 0; r < ROWS; ++r) {
        float v = acc[r] * invdeg_sh[r] + bias;
        out[(size_t)(n0 + r) * D + t] = v;
    }
}

extern "C" void kernel_launch(void* const* d_in, const int* in_sizes, int n_in,
                              void* d_out, int out_size, void* d_ws, size_t ws_size,
                              hipStream_t stream) {
    const float* x      = (const float*)d_in[0];   // [N, D] f32
    const int*   ei     = (const int*)d_in[1];     // [2, E] int32
    const float* lin_w  = (const float*)d_in[2];   // [D_OUT, D_IN] f32
    const float* lin_b  = (const float*)d_in[3];   // [D_OUT] f32
    const float* weight = (const float*)d_in[4];   // [D_OUT, D_OUT] f32
    float* out = (float*)d_out;                    // [N, D] f32

    char* ws = (char*)d_ws;
    const size_t agg_bytes = (size_t)N_NODES * D * sizeof(float);   // 51.2 MB
    const size_t deg_bytes = (size_t)N_NODES * sizeof(u32);         // 400 KB
    float* agg = (float*)ws;
    u32*   deg = (u32*)(ws + agg_bytes);
    float* M   = (float*)(ws + agg_bytes + deg_bytes);
    float* b2  = (float*)(ws + agg_bytes + deg_bytes + (size_t)D * D * sizeof(float));

    // Zero accumulators (ws is re-poisoned to 0xAA before every timed call).
    hipMemsetAsync(d_ws, 0, agg_bytes + deg_bytes, stream);

    precompute_kernel<<<D + 1, 128, 0, stream>>>(lin_w, lin_b, weight, M, b2);
    scatter_kernel<<<N_EDGES / 4, 256, 0, stream>>>(x, ei, agg, deg);
    gemm_kernel<<<N_NODES / ROWS, 128, 0, stream>>>(agg, deg, M, b2, out);
}

// Round 3
// 408.333 us; speedup vs baseline: 2.1236x; 2.1236x over previous
//
#include <hip/hip_runtime.h>

#define N_NODES 100000
#define N_EDGES 800000
#define D 128
#define SCAN_B 98        // ceil(100000 / 1024)

typedef unsigned int u32;

// ---------------------------------------------------------------------------
// M = lin_w.T @ weight (f32), b2 = lin_b @ weight (f32).
// grid = 129 x 128; block 128 handles b2.
// ---------------------------------------------------------------------------
__global__ __launch_bounds__(128) void precompute_kernel(
    const float* __restrict__ lin_w, const float* __restrict__ lin_b,
    const float* __restrict__ weight, float* __restrict__ M, float* __restrict__ b2)
{
    int j = threadIdx.x;
    int i = blockIdx.x;
    if (i < D) {
        float acc = 0.f;
        for (int o = 0; o < D; ++o)
            acc += lin_w[o * D + i] * weight[o * D + j];
        M[i * D + j] = acc;
    } else {
        float acc = 0.f;
        for (int o = 0; o < D; ++o)
            acc += lin_b[o] * weight[o * D + j];
        b2[j] = acc;
    }
}

// --------------------------- CSR build --------------------------------------
__global__ __launch_bounds__(256) void hist_kernel(
    const int* __restrict__ ei, u32* __restrict__ deg)
{
    int e = blockIdx.x * 256 + threadIdx.x;
    if (e < N_EDGES) atomicAdd(deg + ei[e], 1u);
}

// Block-local exclusive scan of deg (1024 elems/block) -> loc, block sums -> bsum.
__global__ __launch_bounds__(256) void scan_up_kernel(
    const u32* __restrict__ deg, u32* __restrict__ loc, u32* __restrict__ bsum)
{
    __shared__ u32 tsum[256];
    int t = threadIdx.x;
    int base = blockIdx.x * 1024 + t * 4;
    u32 v0 = 0, v1 = 0, v2 = 0, v3 = 0;
    if (base + 0 < N_NODES) v0 = deg[base + 0];
    if (base + 1 < N_NODES) v1 = deg[base + 1];
    if (base + 2 < N_NODES) v2 = deg[base + 2];
    if (base + 3 < N_NODES) v3 = deg[base + 3];
    u32 s = v0 + v1 + v2 + v3;
    tsum[t] = s;
    __syncthreads();
    u32 incl = s;
    for (int off = 1; off < 256; off <<= 1) {
        u32 add = (t >= off) ? tsum[t - off] : 0u;
        __syncthreads();
        incl += add;
        tsum[t] = incl;
        __syncthreads();
    }
    u32 excl = incl - s;
    if (base + 0 < N_NODES) loc[base + 0] = excl;
    if (base + 1 < N_NODES) loc[base + 1] = excl + v0;
    if (base + 2 < N_NODES) loc[base + 2] = excl + v0 + v1;
    if (base + 3 < N_NODES) loc[base + 3] = excl + v0 + v1 + v2;
    if (t == 255) bsum[blockIdx.x] = incl;
}

// Exclusive scan of the 98 block sums (single block, LDS Hillis-Steele).
__global__ __launch_bounds__(128) void scan_mid_kernel(u32* __restrict__ bsum)
{
    __shared__ u32 sh[128];
    int t = threadIdx.x;
    u32 v = (t < SCAN_B) ? bsum[t] : 0u;
    sh[t] = v;
    __syncthreads();
    u32 incl = v;
    for (int off = 1; off < 128; off <<= 1) {
        u32 add = (t >= off) ? sh[t - off] : 0u;
        __syncthreads();
        incl += add;
        sh[t] = incl;
        __syncthreads();
    }
    if (t < SCAN_B) bsum[t] = incl - v;   // exclusive
}

// loc += scanned block sum  (loc now = global exclusive offsets = fill cursor)
__global__ __launch_bounds__(256) void scan_add_kernel(
    u32* __restrict__ loc, const u32* __restrict__ bsum)
{
    int base = blockIdx.x * 1024 + threadIdx.x * 4;
    u32 b = bsum[blockIdx.x];
    #pragma unroll
    for (int k = 0; k < 4; ++k)
        if (base + k < N_NODES) loc[base + k] += b;
}

// Scatter col indices into CSR buckets. After this, cursor[n] = row end.
__global__ __launch_bounds__(256) void fill_kernel(
    const int* __restrict__ ei, u32* __restrict__ cursor, int* __restrict__ csr)
{
    int e = blockIdx.x * 256 + threadIdx.x;
    if (e >= N_EDGES) return;
    int row = ei[e];
    int col = ei[N_EDGES + e];
    u32 pos = atomicAdd(cursor + row, 1u);
    csr[pos] = col;
}

// ---------------------------------------------------------------------------
// transform: y = x @ M. 128 threads (thread = column), TROWS rows per block.
// A-values are wave-uniform -> scalar loads; FMA reads them from SGPR.
// ---------------------------------------------------------------------------
#define TROWS 8
__global__ __launch_bounds__(128) void transform_kernel(
    const float* __restrict__ x, const float* __restrict__ M, float* __restrict__ y)
{
    int t = threadIdx.x;
    size_t n0 = (size_t)blockIdx.x * TROWS;
    const float* xb = x + n0 * D;
    float acc[TROWS];
    #pragma unroll
    for (int r = 0; r < TROWS; ++r) acc[r] = 0.f;

    for (int i = 0; i < D; i += 4) {
        float m0 = M[(i + 0) * D + t];
        float m1 = M[(i + 1) * D + t];
        float m2 = M[(i + 2) * D + t];
        float m3 = M[(i + 3) * D + t];
        #pragma unroll
        for (int r = 0; r < TROWS; ++r) {
            const float* xr = xb + r * D + i;
            acc[r] += xr[0] * m0 + xr[1] * m1 + xr[2] * m2 + xr[3] * m3;
        }
    }
    float* yb = y + n0 * D;
    #pragma unroll
    for (int r = 0; r < TROWS; ++r) yb[r * D + t] = acc[r];
}

// ---------------------------------------------------------------------------
// gather: out[n] = (sum_{e in row n} y[csr[e]]) / max(deg,1) + b2.
// One wave per node; lane l holds features 2l, 2l+1. No atomics.
// ---------------------------------------------------------------------------
__global__ __launch_bounds__(256) void gather_kernel(
    const float* __restrict__ y, const int* __restrict__ csr,
    const u32* __restrict__ cursor, const u32* __restrict__ deg,
    const float* __restrict__ b2, float* __restrict__ out)
{
    int wave = (blockIdx.x * 256 + threadIdx.x) >> 6;
    int lane = threadIdx.x & 63;
    if (wave >= N_NODES) return;
    u32 dn = deg[wave];
    u32 end = cursor[wave];          // post-fill cursor = row end
    u32 e = end - dn;                // row start
    float a0 = 0.f, a1 = 0.f;
    // 2-way unroll: two independent row loads in flight
    for (; e + 2 <= end; e += 2) {
        int c0 = csr[e];
        int c1 = csr[e + 1];
        float2 v0 = *(const float2*)(y + (size_t)c0 * D + lane * 2);
        float2 v1 = *(const float2*)(y + (size_t)c1 * D + lane * 2);
        a0 += v0.x + v1.x;
        a1 += v0.y + v1.y;
    }
    if (e < end) {
        int c0 = csr[e];
        float2 v0 = *(const float2*)(y + (size_t)c0 * D + lane * 2);
        a0 += v0.x;
        a1 += v0.y;
    }
    float inv = 1.0f / (float)((dn < 1u) ? 1u : dn);
    float2 b = *(const float2*)(b2 + lane * 2);
    float2 o;
    o.x = a0 * inv + b.x;
    o.y = a1 * inv + b.y;
    *(float2*)(out + (size_t)wave * D + lane * 2) = o;
}

extern "C" void kernel_launch(void* const* d_in, const int* in_sizes, int n_in,
                              void* d_out, int out_size, void* d_ws, size_t ws_size,
                              hipStream_t stream) {
    const float* x      = (const float*)d_in[0];   // [N, D] f32
    const int*   ei     = (const int*)d_in[1];     // [2, E] int32
    const float* lin_w  = (const float*)d_in[2];   // [D_OUT, D_IN] f32
    const float* lin_b  = (const float*)d_in[3];   // [D_OUT] f32
    const float* weight = (const float*)d_in[4];   // [D_OUT, D_OUT] f32
    float* out = (float*)d_out;                    // [N, D] f32

    char* ws = (char*)d_ws;
    const size_t YB  = (size_t)N_NODES * D * sizeof(float);  // 51.2 MB
    const size_t NB4 = (size_t)N_NODES * sizeof(u32);        // 400 KB
    float* y    = (float*)ws;
    u32*   deg  = (u32*)(ws + YB);
    u32*   loc  = (u32*)(ws + YB + NB4);            // becomes cursor after scan_add
    u32*   bsum = (u32*)(ws + YB + 2 * NB4);        // 512 B
    float* M    = (float*)(ws + YB + 2 * NB4 + 512);
    float* b2   = (float*)(ws + YB + 2 * NB4 + 512 + (size_t)D * D * sizeof(float));
    int*   csr  = (int*)(ws + YB + 2 * NB4 + 512 + (size_t)D * D * sizeof(float) + 512);

    hipMemsetAsync(deg, 0, NB4, stream);   // only deg needs zeroing

    precompute_kernel<<<D + 1, 128, 0, stream>>>(lin_w, lin_b, weight, M, b2);
    hist_kernel<<<(N_EDGES + 255) / 256, 256, 0, stream>>>(ei, deg);
    scan_up_kernel<<<SCAN_B, 256, 0, stream>>>(deg, loc, bsum);
    scan_mid_kernel<<<1, 128, 0, stream>>>(bsum);
    scan_add_kernel<<<SCAN_B, 256, 0, stream>>>(loc, bsum);
    fill_kernel<<<(N_EDGES + 255) / 256, 256, 0, stream>>>(ei, loc, csr);
    transform_kernel<<<N_NODES / TROWS, 128, 0, stream>>>(x, M, y);
    gather_kernel<<<(N_NODES + 3) / 4, 256, 0, stream>>>(y, csr, loc, deg, b2, out);
}

// Round 4
// 292.762 us; speedup vs baseline: 2.9619x; 1.3948x over previous
//
#include <hip/hip_runtime.h>

#define N_NODES 100000
#define N_EDGES 800000
#define D 128
#define SCAN_B 98        // ceil(100000 / 1024)

typedef unsigned int u32;
typedef unsigned short u16;
typedef __attribute__((ext_vector_type(8))) short bf16x8;
typedef __attribute__((ext_vector_type(4))) float f32x4;

static __device__ __forceinline__ short f2bf(float f) {
    u32 u = __float_as_uint(f);
    u += 0x7FFFu + ((u >> 16) & 1u);     // round-to-nearest-even
    return (short)(u >> 16);
}

// ---------------------------------------------------------------------------
// Precompute Mfrag (bf16 B-fragments of M = lin_w.T @ weight) and b2 = lin_b @ weight.
// Mfrag element for M[k][n]:  ct=n>>4, ks=k>>5, lane=((k>>3)&3)*16+(n&15), j=k&7
//   index = ((ct*4+ks)*64 + lane)*8 + j     (32 KB total, L2-resident)
// grid = 129 x 128; block 128 handles b2; blockIdx = k row of M.
// ---------------------------------------------------------------------------
__global__ __launch_bounds__(128) void precompute_kernel(
    const float* __restrict__ lin_w, const float* __restrict__ lin_b,
    const float* __restrict__ weight, u16* __restrict__ Mfrag, float* __restrict__ b2)
{
    int n = threadIdx.x;
    int k = blockIdx.x;
    if (k < D) {
        float acc = 0.f;
        for (int o = 0; o < D; ++o)
            acc += lin_w[o * D + k] * weight[o * D + n];
        int idx = ((((n >> 4) * 4 + (k >> 5)) * 64) + ((k >> 3) & 3) * 16 + (n & 15)) * 8 + (k & 7);
        Mfrag[idx] = (u16)f2bf(acc);
    } else {
        float acc = 0.f;
        for (int o = 0; o < D; ++o)
            acc += lin_b[o] * weight[o * D + n];
        b2[n] = acc;
    }
}

// --------------------------- CSR build --------------------------------------
__global__ __launch_bounds__(256) void hist_kernel(
    const int* __restrict__ ei, u32* __restrict__ deg)
{
    int e = blockIdx.x * 256 + threadIdx.x;
    if (e < N_EDGES) atomicAdd(deg + ei[e], 1u);
}

__global__ __launch_bounds__(256) void scan_up_kernel(
    const u32* __restrict__ deg, u32* __restrict__ loc, u32* __restrict__ bsum)
{
    __shared__ u32 tsum[256];
    int t = threadIdx.x;
    int base = blockIdx.x * 1024 + t * 4;
    u32 v0 = 0, v1 = 0, v2 = 0, v3 = 0;
    if (base + 0 < N_NODES) v0 = deg[base + 0];
    if (base + 1 < N_NODES) v1 = deg[base + 1];
    if (base + 2 < N_NODES) v2 = deg[base + 2];
    if (base + 3 < N_NODES) v3 = deg[base + 3];
    u32 s = v0 + v1 + v2 + v3;
    tsum[t] = s;
    __syncthreads();
    u32 incl = s;
    for (int off = 1; off < 256; off <<= 1) {
        u32 add = (t >= off) ? tsum[t - off] : 0u;
        __syncthreads();
        incl += add;
        tsum[t] = incl;
        __syncthreads();
    }
    u32 excl = incl - s;
    if (base + 0 < N_NODES) loc[base + 0] = excl;
    if (base + 1 < N_NODES) loc[base + 1] = excl + v0;
    if (base + 2 < N_NODES) loc[base + 2] = excl + v0 + v1;
    if (base + 3 < N_NODES) loc[base + 3] = excl + v0 + v1 + v2;
    if (t == 255) bsum[blockIdx.x] = incl;
}

__global__ __launch_bounds__(128) void scan_mid_kernel(u32* __restrict__ bsum)
{
    __shared__ u32 sh[128];
    int t = threadIdx.x;
    u32 v = (t < SCAN_B) ? bsum[t] : 0u;
    sh[t] = v;
    __syncthreads();
    u32 incl = v;
    for (int off = 1; off < 128; off <<= 1) {
        u32 add = (t >= off) ? sh[t - off] : 0u;
        __syncthreads();
        incl += add;
        sh[t] = incl;
        __syncthreads();
    }
    if (t < SCAN_B) bsum[t] = incl - v;   // exclusive
}

__global__ __launch_bounds__(256) void scan_add_kernel(
    u32* __restrict__ loc, const u32* __restrict__ bsum)
{
    int base = blockIdx.x * 1024 + threadIdx.x * 4;
    u32 b = bsum[blockIdx.x];
    #pragma unroll
    for (int k = 0; k < 4; ++k)
        if (base + k < N_NODES) loc[base + k] += b;
}

__global__ __launch_bounds__(256) void fill_kernel(
    const int* __restrict__ ei, u32* __restrict__ cursor, int* __restrict__ csr)
{
    int e = blockIdx.x * 256 + threadIdx.x;
    if (e >= N_EDGES) return;
    int row = ei[e];
    int col = ei[N_EDGES + e];
    u32 pos = atomicAdd(cursor + row, 1u);
    csr[pos] = col;
}

// ---------------------------------------------------------------------------
// transform: y = x @ M via mfma_f32_16x16x32_bf16.
// 256 threads = 4 waves; block tile 32 rows x 128 cols.
// wave w: row-tile (w&1)*16, col-half (w>>1)*64 (4 col-tiles of 16).
// A: f32 x loaded as 2x float4, RNE-cvt to bf16x8 (A[m=lane&15][k=quad*8+j]).
// B: preswizzled Mfrag, one dwordx4 per (coltile,kstep) per lane.
// D: y[row0 + quad*4 + reg][ctg*16 + (lane&15)], f32.
// ---------------------------------------------------------------------------
__global__ __launch_bounds__(256) void transform_mfma_kernel(
    const float* __restrict__ x, const u16* __restrict__ Mfrag, float* __restrict__ y)
{
    int t = threadIdx.x;
    int wave = t >> 6, lane = t & 63;
    int rt = wave & 1, ch = wave >> 1;
    int quad = lane >> 4, mrow = lane & 15;
    int row0 = blockIdx.x * 32 + rt * 16;

    const float* xr = x + (size_t)(row0 + mrow) * D + quad * 8;

    f32x4 acc0 = {0.f, 0.f, 0.f, 0.f};
    f32x4 acc1 = {0.f, 0.f, 0.f, 0.f};
    f32x4 acc2 = {0.f, 0.f, 0.f, 0.f};
    f32x4 acc3 = {0.f, 0.f, 0.f, 0.f};

    #pragma unroll
    for (int ks = 0; ks < 4; ++ks) {
        float4 lo = *(const float4*)(xr + ks * 32);
        float4 hi = *(const float4*)(xr + ks * 32 + 4);
        bf16x8 a;
        a[0] = f2bf(lo.x); a[1] = f2bf(lo.y); a[2] = f2bf(lo.z); a[3] = f2bf(lo.w);
        a[4] = f2bf(hi.x); a[5] = f2bf(hi.y); a[6] = f2bf(hi.z); a[7] = f2bf(hi.w);

        const bf16x8* mb = (const bf16x8*)(Mfrag) + ((ch * 4) * 4 + ks) * 64 + lane;
        // consecutive col-tiles are 4*64 frags apart
        bf16x8 b0 = mb[0 * 256];
        bf16x8 b1 = mb[1 * 256];
        bf16x8 b2f = mb[2 * 256];
        bf16x8 b3 = mb[3 * 256];
        acc0 = __builtin_amdgcn_mfma_f32_16x16x32_bf16(a, b0, acc0, 0, 0, 0);
        acc1 = __builtin_amdgcn_mfma_f32_16x16x32_bf16(a, b1, acc1, 0, 0, 0);
        acc2 = __builtin_amdgcn_mfma_f32_16x16x32_bf16(a, b2f, acc2, 0, 0, 0);
        acc3 = __builtin_amdgcn_mfma_f32_16x16x32_bf16(a, b3, acc3, 0, 0, 0);
    }

    float* yb = y + (size_t)(row0 + quad * 4) * D + ch * 64 + mrow;
    #pragma unroll
    for (int r = 0; r < 4; ++r) {
        yb[(size_t)r * D + 0 * 16] = acc0[r];
        yb[(size_t)r * D + 1 * 16] = acc1[r];
        yb[(size_t)r * D + 2 * 16] = acc2[r];
        yb[(size_t)r * D + 3 * 16] = acc3[r];
    }
}

// ---------------------------------------------------------------------------
// gather: out[n] = (sum_{e in row n} y[csr[e]]) / max(deg,1) + b2.
// One wave per node; lane l = features 2l,2l+1; 4-way unrolled loads.
// ---------------------------------------------------------------------------
__global__ __launch_bounds__(256) void gather_kernel(
    const float* __restrict__ y, const int* __restrict__ csr,
    const u32* __restrict__ cursor, const u32* __restrict__ deg,
    const float* __restrict__ b2, float* __restrict__ out)
{
    int wave = (blockIdx.x * 256 + threadIdx.x) >> 6;
    int lane = threadIdx.x & 63;
    if (wave >= N_NODES) return;
    u32 dn = deg[wave];
    u32 end = cursor[wave];          // post-fill cursor = row end
    u32 e = end - dn;                // row start
    float a0 = 0.f, a1 = 0.f;
    for (; e + 4 <= end; e += 4) {
        int c0 = csr[e + 0];
        int c1 = csr[e + 1];
        int c2 = csr[e + 2];
        int c3 = csr[e + 3];
        float2 v0 = *(const float2*)(y + (size_t)c0 * D + lane * 2);
        float2 v1 = *(const float2*)(y + (size_t)c1 * D + lane * 2);
        float2 v2 = *(const float2*)(y + (size_t)c2 * D + lane * 2);
        float2 v3 = *(const float2*)(y + (size_t)c3 * D + lane * 2);
        a0 += (v0.x + v1.x) + (v2.x + v3.x);
        a1 += (v0.y + v1.y) + (v2.y + v3.y);
    }
    for (; e < end; ++e) {
        int c0 = csr[e];
        float2 v0 = *(const float2*)(y + (size_t)c0 * D + lane * 2);
        a0 += v0.x;
        a1 += v0.y;
    }
    float inv = 1.0f / (float)((dn < 1u) ? 1u : dn);
    float2 b = *(const float2*)(b2 + lane * 2);
    float2 o;
    o.x = a0 * inv + b.x;
    o.y = a1 * inv + b.y;
    *(float2*)(out + (size_t)wave * D + lane * 2) = o;
}

extern "C" void kernel_launch(void* const* d_in, const int* in_sizes, int n_in,
                              void* d_out, int out_size, void* d_ws, size_t ws_size,
                              hipStream_t stream) {
    const float* x      = (const float*)d_in[0];   // [N, D] f32
    const int*   ei     = (const int*)d_in[1];     // [2, E] int32
    const float* lin_w  = (const float*)d_in[2];   // [D_OUT, D_IN] f32
    const float* lin_b  = (const float*)d_in[3];   // [D_OUT] f32
    const float* weight = (const float*)d_in[4];   // [D_OUT, D_OUT] f32
    float* out = (float*)d_out;                    // [N, D] f32

    char* ws = (char*)d_ws;
    const size_t YB  = (size_t)N_NODES * D * sizeof(float);  // 51.2 MB
    const size_t NB4 = (size_t)N_NODES * sizeof(u32);        // 400 KB
    float* y     = (float*)ws;
    u32*   deg   = (u32*)(ws + YB);
    u32*   loc   = (u32*)(ws + YB + NB4);           // becomes cursor after scan_add
    u32*   bsum  = (u32*)(ws + YB + 2 * NB4);       // 512 B
    u16*   Mfrag = (u16*)(ws + YB + 2 * NB4 + 512); // 32 KB
    float* b2    = (float*)(ws + YB + 2 * NB4 + 512 + 32768);
    int*   csr   = (int*)(ws + YB + 2 * NB4 + 512 + 32768 + 512);

    hipMemsetAsync(deg, 0, NB4, stream);   // only deg needs zeroing

    precompute_kernel<<<D + 1, 128, 0, stream>>>(lin_w, lin_b, weight, Mfrag, b2);
    hist_kernel<<<(N_EDGES + 255) / 256, 256, 0, stream>>>(ei, deg);
    scan_up_kernel<<<SCAN_B, 256, 0, stream>>>(deg, loc, bsum);
    scan_mid_kernel<<<1, 128, 0, stream>>>(bsum);
    scan_add_kernel<<<SCAN_B, 256, 0, stream>>>(loc, bsum);
    fill_kernel<<<(N_EDGES + 255) / 256, 256, 0, stream>>>(ei, loc, csr);
    transform_mfma_kernel<<<N_NODES / 32, 256, 0, stream>>>(x, Mfrag, y);
    gather_kernel<<<(N_NODES + 3) / 4, 256, 0, stream>>>(y, csr, loc, deg, b2, out);
}

// Round 6
// 242.927 us; speedup vs baseline: 3.5695x; 1.2051x over previous
//
#include <hip/hip_runtime.h>

#define N_NODES 100000
#define N_EDGES 800000
#define D 128
#define SCAN_B 98        // ceil(100000 / 1024)

typedef unsigned int u32;
typedef unsigned short u16;
typedef __attribute__((ext_vector_type(8))) short bf16x8;
typedef __attribute__((ext_vector_type(4))) float f32x4;

static __device__ __forceinline__ short f2bf(float f) {
    u32 u = __float_as_uint(f);
    u += 0x7FFFu + ((u >> 16) & 1u);     // round-to-nearest-even
    return (short)(u >> 16);
}
static __device__ __forceinline__ float bf_lo(u32 u) { return __uint_as_float(u << 16); }
static __device__ __forceinline__ float bf_hi(u32 u) { return __uint_as_float(u & 0xFFFF0000u); }

// ---------------------------------------------------------------------------
// K2: histogram (blocks 0..895) | Mfrag precompute (896..959) | b2 (960).
// ---------------------------------------------------------------------------
__global__ __launch_bounds__(256) void hist_pre_kernel(
    const int* __restrict__ ei,
    const float* __restrict__ lin_w, const float* __restrict__ lin_b,
    const float* __restrict__ weight,
    u32* __restrict__ deg, u16* __restrict__ Mfrag, float* __restrict__ b2)
{
    int t = threadIdx.x;
    int blk = blockIdx.x;
    if (blk < 896) {
        for (int e = blk * 256 + t; e < N_EDGES; e += 896 * 256)
            atomicAdd(deg + ei[e], 1u);
    } else if (blk < 960) {
        // M = lin_w.T @ weight, bf16 B-fragment swizzle (validated in R3/R4).
        int kk = (blk - 896) * 2 + (t >> 7);
        int n = t & 127;
        float acc = 0.f;
        for (int o = 0; o < D; ++o)
            acc += lin_w[o * D + kk] * weight[o * D + n];
        int idx = ((((n >> 4) * 4 + (kk >> 5)) * 64) + ((kk >> 3) & 3) * 16 + (n & 15)) * 8 + (kk & 7);
        Mfrag[idx] = (u16)f2bf(acc);
    } else if (blk == 960 && t < D) {
        float acc = 0.f;
        for (int o = 0; o < D; ++o)
            acc += lin_b[o] * weight[o * D + t];
        b2[t] = acc;
    }
}

// ---------------------------------------------------------------------------
// K3: block-local exclusive scan of deg (1024/block) -> loc, block sum -> bsum.
// ---------------------------------------------------------------------------
__global__ __launch_bounds__(256) void scan_up_kernel(
    const u32* __restrict__ deg, u32* __restrict__ loc, u32* __restrict__ bsum)
{
    __shared__ u32 tsum[256];
    int t = threadIdx.x;
    int base = blockIdx.x * 1024 + t * 4;
    u32 v0 = 0, v1 = 0, v2 = 0, v3 = 0;
    if (base + 0 < N_NODES) v0 = deg[base + 0];
    if (base + 1 < N_NODES) v1 = deg[base + 1];
    if (base + 2 < N_NODES) v2 = deg[base + 2];
    if (base + 3 < N_NODES) v3 = deg[base + 3];
    u32 s = v0 + v1 + v2 + v3;
    tsum[t] = s;
    __syncthreads();
    u32 incl = s;
    for (int off = 1; off < 256; off <<= 1) {
        u32 add = (t >= off) ? tsum[t - off] : 0u;
        __syncthreads();
        incl += add;
        tsum[t] = incl;
        __syncthreads();
    }
    u32 excl = incl - s;
    if (base + 0 < N_NODES) loc[base + 0] = excl;
    if (base + 1 < N_NODES) loc[base + 1] = excl + v0;
    if (base + 2 < N_NODES) loc[base + 2] = excl + v0 + v1;
    if (base + 3 < N_NODES) loc[base + 3] = excl + v0 + v1 + v2;
    if (t == 255) bsum[blockIdx.x] = incl;
}

// ---------------------------------------------------------------------------
// K4: each block computes its own global prefix (sum of bsum[0..blk-1]) in LDS
// and adds it to its 1024 loc entries. Replaces scan_mid + scan_add.
// ---------------------------------------------------------------------------
__global__ __launch_bounds__(256) void scan_fix_kernel(
    u32* __restrict__ loc, const u32* __restrict__ bsum)
{
    __shared__ u32 sh[256];
    int t = threadIdx.x;
    int blk = blockIdx.x;
    sh[t] = (t < blk) ? bsum[t] : 0u;     // blk < 98 <= 256
    __syncthreads();
    for (int off = 128; off > 0; off >>= 1) {
        if (t < off) sh[t] += sh[t + off];
        __syncthreads();
    }
    u32 S = sh[0];
    int base = blk * 1024 + t * 4;
    #pragma unroll
    for (int k = 0; k < 4; ++k)
        if (base + k < N_NODES) loc[base + k] += S;
}

// ---------------------------------------------------------------------------
// K5: fill CSR (exactly 1 edge/thread: 3125*256 = 800000), then transform
// y = x @ M via MFMA (1 tile of 32 rows per block: 3125 tiles). Independent
// phases — no internal sync needed. y stored bf16.
// ---------------------------------------------------------------------------
__global__ __launch_bounds__(256) void fill_transform_kernel(
    const int* __restrict__ ei, u32* __restrict__ cursor, int* __restrict__ csr,
    const float* __restrict__ x, const u16* __restrict__ Mfrag, u16* __restrict__ y)
{
    int t = threadIdx.x;
    int blk = blockIdx.x;

    // ---- fill ----
    {
        int e = blk * 256 + t;           // exact cover of 800000
        int row = ei[e];
        int col = ei[N_EDGES + e];
        u32 pos = atomicAdd(cursor + row, 1u);
        csr[pos] = col;
    }

    // ---- transform ----
    int wave = t >> 6, lane = t & 63;
    int rt = wave & 1, ch = wave >> 1;
    int quad = lane >> 4, mrow = lane & 15;
    int row0 = blk * 32 + rt * 16;

    const float* xr = x + (size_t)(row0 + mrow) * D + quad * 8;

    f32x4 acc0 = {0.f, 0.f, 0.f, 0.f};
    f32x4 acc1 = {0.f, 0.f, 0.f, 0.f};
    f32x4 acc2 = {0.f, 0.f, 0.f, 0.f};
    f32x4 acc3 = {0.f, 0.f, 0.f, 0.f};

    #pragma unroll
    for (int ks = 0; ks < 4; ++ks) {
        float4 lo = *(const float4*)(xr + ks * 32);
        float4 hi = *(const float4*)(xr + ks * 32 + 4);
        bf16x8 a;
        a[0] = f2bf(lo.x); a[1] = f2bf(lo.y); a[2] = f2bf(lo.z); a[3] = f2bf(lo.w);
        a[4] = f2bf(hi.x); a[5] = f2bf(hi.y); a[6] = f2bf(hi.z); a[7] = f2bf(hi.w);

        const bf16x8* mb = (const bf16x8*)(Mfrag) + ((ch * 4) * 4 + ks) * 64 + lane;
        bf16x8 b0 = mb[0 * 256];
        bf16x8 b1 = mb[1 * 256];
        bf16x8 b2f = mb[2 * 256];
        bf16x8 b3 = mb[3 * 256];
        acc0 = __builtin_amdgcn_mfma_f32_16x16x32_bf16(a, b0, acc0, 0, 0, 0);
        acc1 = __builtin_amdgcn_mfma_f32_16x16x32_bf16(a, b1, acc1, 0, 0, 0);
        acc2 = __builtin_amdgcn_mfma_f32_16x16x32_bf16(a, b2f, acc2, 0, 0, 0);
        acc3 = __builtin_amdgcn_mfma_f32_16x16x32_bf16(a, b3, acc3, 0, 0, 0);
    }

    u16* yb = y + (size_t)(row0 + quad * 4) * D + ch * 64 + mrow;
    #pragma unroll
    for (int r = 0; r < 4; ++r) {
        yb[(size_t)r * D + 0 * 16] = (u16)f2bf(acc0[r]);
        yb[(size_t)r * D + 1 * 16] = (u16)f2bf(acc1[r]);
        yb[(size_t)r * D + 2 * 16] = (u16)f2bf(acc2[r]);
        yb[(size_t)r * D + 3 * 16] = (u16)f2bf(acc3[r]);
    }
}

// ---------------------------------------------------------------------------
// K6: gather. out[n] = (sum y_bf16[nbr]) / max(deg,1) + b2. One wave/node.
// ---------------------------------------------------------------------------
__global__ __launch_bounds__(256) void gather_kernel(
    const u16* __restrict__ y, const int* __restrict__ csr,
    const u32* __restrict__ cursor, const u32* __restrict__ deg,
    const float* __restrict__ b2, float* __restrict__ out)
{
    int n = (blockIdx.x * 256 + threadIdx.x) >> 6;
    int lane = threadIdx.x & 63;
    if (n >= N_NODES) return;
    u32 dn = deg[n];
    u32 end = cursor[n];             // post-fill cursor = row end
    u32 e = end - dn;                // row start
    const u32* yw = (const u32*)y;   // row stride 64 u32
    float a0 = 0.f, a1 = 0.f;
    for (; e + 4 <= end; e += 4) {
        int c0 = csr[e + 0];
        int c1 = csr[e + 1];
        int c2 = csr[e + 2];
        int c3 = csr[e + 3];
        u32 u0 = yw[(size_t)c0 * 64 + lane];
        u32 u1 = yw[(size_t)c1 * 64 + lane];
        u32 u2 = yw[(size_t)c2 * 64 + lane];
        u32 u3 = yw[(size_t)c3 * 64 + lane];
        a0 += (bf_lo(u0) + bf_lo(u1)) + (bf_lo(u2) + bf_lo(u3));
        a1 += (bf_hi(u0) + bf_hi(u1)) + (bf_hi(u2) + bf_hi(u3));
    }
    for (; e < end; ++e) {
        u32 u0 = yw[(size_t)csr[e] * 64 + lane];
        a0 += bf_lo(u0);
        a1 += bf_hi(u0);
    }
    float inv = 1.0f / (float)((dn < 1u) ? 1u : dn);
    float2 b = *(const float2*)(b2 + lane * 2);
    float2 o;
    o.x = a0 * inv + b.x;
    o.y = a1 * inv + b.y;
    *(float2*)(out + (size_t)n * D + lane * 2) = o;
}

extern "C" void kernel_launch(void* const* d_in, const int* in_sizes, int n_in,
                              void* d_out, int out_size, void* d_ws, size_t ws_size,
                              hipStream_t stream) {
    const float* x      = (const float*)d_in[0];   // [N, D] f32
    const int*   ei     = (const int*)d_in[1];     // [2, E] int32
    const float* lin_w  = (const float*)d_in[2];   // [D_OUT, D_IN] f32
    const float* lin_b  = (const float*)d_in[3];   // [D_OUT] f32
    const float* weight = (const float*)d_in[4];   // [D_OUT, D_OUT] f32
    float* out = (float*)d_out;                    // [N, D] f32

    char* ws = (char*)d_ws;
    const size_t YB2 = (size_t)N_NODES * D * sizeof(u16);   // 25.6 MB (bf16 y)
    const size_t NB4 = (size_t)N_NODES * sizeof(u32);       // 400 KB
    u16*   y     = (u16*)ws;
    u32*   deg   = (u32*)(ws + YB2);
    u32*   loc   = (u32*)(ws + YB2 + NB4);                  // cursor after fill
    u32*   bsum  = (u32*)(ws + YB2 + 2 * NB4);              // 512 B
    u16*   Mfrag = (u16*)(ws + YB2 + 2 * NB4 + 512);        // 32 KB
    float* b2    = (float*)(ws + YB2 + 2 * NB4 + 512 + 32768);
    int*   csr   = (int*)(ws + YB2 + 2 * NB4 + 512 + 32768 + 512);

    hipMemsetAsync(deg, 0, NB4, stream);   // only deg needs zeroing

    hist_pre_kernel<<<1024, 256, 0, stream>>>(ei, lin_w, lin_b, weight, deg, Mfrag, b2);
    scan_up_kernel<<<SCAN_B, 256, 0, stream>>>(deg, loc, bsum);
    scan_fix_kernel<<<SCAN_B, 256, 0, stream>>>(loc, bsum);
    fill_transform_kernel<<<N_NODES / 32, 256, 0, stream>>>(ei, loc, csr, x, Mfrag, y);
    gather_kernel<<<(N_NODES + 3) / 4, 256, 0, stream>>>(y, csr, loc, deg, b2, out);
}

// Round 7
// 231.795 us; speedup vs baseline: 3.7409x; 1.0480x over previous
//
#include <hip/hip_runtime.h>

#define N_NODES 100000
#define N_EDGES 800000
#define D 128
#define SCAN_B 98        // ceil(100000 / 1024)
#define YSTRIDE 132      // padded LDS row stride (f32): 2-way bank alias only

typedef unsigned int u32;
typedef unsigned short u16;
typedef __attribute__((ext_vector_type(8))) short bf16x8;
typedef __attribute__((ext_vector_type(4))) float f32x4;

static __device__ __forceinline__ short f2bf(float f) {
    u32 u = __float_as_uint(f);
    u += 0x7FFFu + ((u >> 16) & 1u);     // round-to-nearest-even
    return (short)(u >> 16);
}
static __device__ __forceinline__ u32 pack2(float lo, float hi) {
    return (u32)(u16)f2bf(lo) | ((u32)(u16)f2bf(hi) << 16);
}
static __device__ __forceinline__ float bf_lo(u32 u) { return __uint_as_float(u << 16); }
static __device__ __forceinline__ float bf_hi(u32 u) { return __uint_as_float(u & 0xFFFF0000u); }

// ---------------------------------------------------------------------------
// K2: histogram (blocks 0..895) | Mfrag precompute (896..959) | b2 (960).
// ---------------------------------------------------------------------------
__global__ __launch_bounds__(256) void hist_pre_kernel(
    const int* __restrict__ ei,
    const float* __restrict__ lin_w, const float* __restrict__ lin_b,
    const float* __restrict__ weight,
    u32* __restrict__ deg, u16* __restrict__ Mfrag, float* __restrict__ b2)
{
    int t = threadIdx.x;
    int blk = blockIdx.x;
    if (blk < 896) {
        for (int e = blk * 256 + t; e < N_EDGES; e += 896 * 256)
            atomicAdd(deg + ei[e], 1u);
    } else if (blk < 960) {
        // M = lin_w.T @ weight, bf16 B-fragment swizzle (validated R3-R6).
        int kk = (blk - 896) * 2 + (t >> 7);
        int n = t & 127;
        float acc = 0.f;
        for (int o = 0; o < D; ++o)
            acc += lin_w[o * D + kk] * weight[o * D + n];
        int idx = ((((n >> 4) * 4 + (kk >> 5)) * 64) + ((kk >> 3) & 3) * 16 + (n & 15)) * 8 + (kk & 7);
        Mfrag[idx] = (u16)f2bf(acc);
    } else if (blk == 960 && t < D) {
        float acc = 0.f;
        for (int o = 0; o < D; ++o)
            acc += lin_b[o] * weight[o * D + t];
        b2[t] = acc;
    }
}

// ---------------------------------------------------------------------------
// K3: block-local exclusive scan of deg (1024/block) -> loc, block sum -> bsum.
// ---------------------------------------------------------------------------
__global__ __launch_bounds__(256) void scan_up_kernel(
    const u32* __restrict__ deg, u32* __restrict__ loc, u32* __restrict__ bsum)
{
    __shared__ u32 tsum[256];
    int t = threadIdx.x;
    int base = blockIdx.x * 1024 + t * 4;
    u32 v0 = 0, v1 = 0, v2 = 0, v3 = 0;
    if (base + 0 < N_NODES) v0 = deg[base + 0];
    if (base + 1 < N_NODES) v1 = deg[base + 1];
    if (base + 2 < N_NODES) v2 = deg[base + 2];
    if (base + 3 < N_NODES) v3 = deg[base + 3];
    u32 s = v0 + v1 + v2 + v3;
    tsum[t] = s;
    __syncthreads();
    u32 incl = s;
    for (int off = 1; off < 256; off <<= 1) {
        u32 add = (t >= off) ? tsum[t - off] : 0u;
        __syncthreads();
        incl += add;
        tsum[t] = incl;
        __syncthreads();
    }
    u32 excl = incl - s;
    if (base + 0 < N_NODES) loc[base + 0] = excl;
    if (base + 1 < N_NODES) loc[base + 1] = excl + v0;
    if (base + 2 < N_NODES) loc[base + 2] = excl + v0 + v1;
    if (base + 3 < N_NODES) loc[base + 3] = excl + v0 + v1 + v2;
    if (t == 255) bsum[blockIdx.x] = incl;
}

// ---------------------------------------------------------------------------
// K4: each block sums bsum[0..blk-1] in LDS and adds to its 1024 loc entries.
// ---------------------------------------------------------------------------
__global__ __launch_bounds__(256) void scan_fix_kernel(
    u32* __restrict__ loc, const u32* __restrict__ bsum)
{
    __shared__ u32 sh[256];
    int t = threadIdx.x;
    int blk = blockIdx.x;
    sh[t] = (t < blk) ? bsum[t] : 0u;     // blk < 98 <= 256
    __syncthreads();
    for (int off = 128; off > 0; off >>= 1) {
        if (t < off) sh[t] += sh[t + off];
        __syncthreads();
    }
    u32 S = sh[0];
    int base = blk * 1024 + t * 4;
    #pragma unroll
    for (int k = 0; k < 4; ++k)
        if (base + k < N_NODES) loc[base + k] += S;
}

// ---------------------------------------------------------------------------
// K5: fill CSR (1 edge/thread) + transform y = x @ M via MFMA.
// y accumulators round-trip through LDS so global y stores are fully
// coalesced (2x dwordx4 per thread) -- fixes the 2x write amplification of
// direct D-layout u16 scatter stores.
// ---------------------------------------------------------------------------
__global__ __launch_bounds__(256) void fill_transform_kernel(
    const int* __restrict__ ei, u32* __restrict__ cursor, int* __restrict__ csr,
    const float* __restrict__ x, const u16* __restrict__ Mfrag, u16* __restrict__ y)
{
    __shared__ float shY[32 * YSTRIDE];   // 16.9 KB
    int t = threadIdx.x;
    int blk = blockIdx.x;

    // ---- fill (exact cover: 3125*256 = 800000) ----
    {
        int e = blk * 256 + t;
        int row = ei[e];
        int col = ei[N_EDGES + e];
        u32 pos = atomicAdd(cursor + row, 1u);
        csr[pos] = col;
    }

    // ---- transform ----
    int wave = t >> 6, lane = t & 63;
    int rt = wave & 1, ch = wave >> 1;
    int quad = lane >> 4, mrow = lane & 15;
    int row0 = blk * 32 + rt * 16;

    const float* xr = x + (size_t)(row0 + mrow) * D + quad * 8;

    f32x4 acc0 = {0.f, 0.f, 0.f, 0.f};
    f32x4 acc1 = {0.f, 0.f, 0.f, 0.f};
    f32x4 acc2 = {0.f, 0.f, 0.f, 0.f};
    f32x4 acc3 = {0.f, 0.f, 0.f, 0.f};

    #pragma unroll
    for (int ks = 0; ks < 4; ++ks) {
        float4 lo = *(const float4*)(xr + ks * 32);
        float4 hi = *(const float4*)(xr + ks * 32 + 4);
        bf16x8 a;
        a[0] = f2bf(lo.x); a[1] = f2bf(lo.y); a[2] = f2bf(lo.z); a[3] = f2bf(lo.w);
        a[4] = f2bf(hi.x); a[5] = f2bf(hi.y); a[6] = f2bf(hi.z); a[7] = f2bf(hi.w);

        const bf16x8* mb = (const bf16x8*)(Mfrag) + ((ch * 4) * 4 + ks) * 64 + lane;
        bf16x8 b0 = mb[0 * 256];
        bf16x8 b1 = mb[1 * 256];
        bf16x8 b2f = mb[2 * 256];
        bf16x8 b3 = mb[3 * 256];
        acc0 = __builtin_amdgcn_mfma_f32_16x16x32_bf16(a, b0, acc0, 0, 0, 0);
        acc1 = __builtin_amdgcn_mfma_f32_16x16x32_bf16(a, b1, acc1, 0, 0, 0);
        acc2 = __builtin_amdgcn_mfma_f32_16x16x32_bf16(a, b2f, acc2, 0, 0, 0);
        acc3 = __builtin_amdgcn_mfma_f32_16x16x32_bf16(a, b3, acc3, 0, 0, 0);
    }

    // stage D-layout accumulators into LDS (f32)
    {
        float* dst = shY + (size_t)(rt * 16 + quad * 4) * YSTRIDE + ch * 64 + mrow;
        #pragma unroll
        for (int r = 0; r < 4; ++r) {
            dst[r * YSTRIDE + 0 * 16] = acc0[r];
            dst[r * YSTRIDE + 1 * 16] = acc1[r];
            dst[r * YSTRIDE + 2 * 16] = acc2[r];
            dst[r * YSTRIDE + 3 * 16] = acc3[r];
        }
    }
    __syncthreads();

    // coalesced write-out: thread t -> row t>>3, 16 cols starting at (t&7)*16
    {
        int orow = t >> 3, seg = t & 7;
        const float* src = shY + (size_t)orow * YSTRIDE + seg * 16;
        u32 p[8];
        #pragma unroll
        for (int i = 0; i < 8; ++i)
            p[i] = pack2(src[2 * i], src[2 * i + 1]);
        u32* dst = (u32*)y + ((size_t)(blk * 32 + orow) * 64 + seg * 8);
        *(uint4*)(dst + 0) = make_uint4(p[0], p[1], p[2], p[3]);
        *(uint4*)(dst + 4) = make_uint4(p[4], p[5], p[6], p[7]);
    }
}

// ---------------------------------------------------------------------------
// K6: gather. Half-wave (32 lanes) per node -> 2 independent node streams per
// wave; lane sl covers cols 4sl..4sl+3 via uint2 loads; 4-deep unroll = 8
// concurrent row loads per wave. out written as coalesced float4.
// ---------------------------------------------------------------------------
__global__ __launch_bounds__(256) void gather_kernel(
    const u16* __restrict__ y, const int* __restrict__ csr,
    const u32* __restrict__ cursor, const u32* __restrict__ deg,
    const float* __restrict__ b2, float* __restrict__ out)
{
    int idx = blockIdx.x * 256 + threadIdx.x;
    int n = idx >> 5;                 // half-wave id = node
    int sl = idx & 31;
    if (n >= N_NODES) return;
    u32 dn = deg[n];
    u32 end = cursor[n];              // post-fill cursor = row end
    u32 e = end - dn;                 // row start
    const u32* yw = (const u32*)y;    // row stride 64 u32
    float a0 = 0.f, a1 = 0.f, a2 = 0.f, a3 = 0.f;
    for (; e + 4 <= end; e += 4) {
        int c0 = csr[e + 0];
        int c1 = csr[e + 1];
        int c2 = csr[e + 2];
        int c3 = csr[e + 3];
        uint2 u0 = *(const uint2*)(yw + (size_t)c0 * 64 + sl * 2);
        uint2 u1 = *(const uint2*)(yw + (size_t)c1 * 64 + sl * 2);
        uint2 u2 = *(const uint2*)(yw + (size_t)c2 * 64 + sl * 2);
        uint2 u3 = *(const uint2*)(yw + (size_t)c3 * 64 + sl * 2);
        a0 += (bf_lo(u0.x) + bf_lo(u1.x)) + (bf_lo(u2.x) + bf_lo(u3.x));
        a1 += (bf_hi(u0.x) + bf_hi(u1.x)) + (bf_hi(u2.x) + bf_hi(u3.x));
        a2 += (bf_lo(u0.y) + bf_lo(u1.y)) + (bf_lo(u2.y) + bf_lo(u3.y));
        a3 += (bf_hi(u0.y) + bf_hi(u1.y)) + (bf_hi(u2.y) + bf_hi(u3.y));
    }
    for (; e < end; ++e) {
        uint2 u0 = *(const uint2*)(yw + (size_t)csr[e] * 64 + sl * 2);
        a0 += bf_lo(u0.x);
        a1 += bf_hi(u0.x);
        a2 += bf_lo(u0.y);
        a3 += bf_hi(u0.y);
    }
    float inv = 1.0f / (float)((dn < 1u) ? 1u : dn);
    float4 b = *(const float4*)(b2 + sl * 4);
    float4 o;
    o.x = a0 * inv + b.x;
    o.y = a1 * inv + b.y;
    o.z = a2 * inv + b.z;
    o.w = a3 * inv + b.w;
    *(float4*)(out + (size_t)n * D + sl * 4) = o;
}

extern "C" void kernel_launch(void* const* d_in, const int* in_sizes, int n_in,
                              void* d_out, int out_size, void* d_ws, size_t ws_size,
                              hipStream_t stream) {
    const float* x      = (const float*)d_in[0];   // [N, D] f32
    const int*   ei     = (const int*)d_in[1];     // [2, E] int32
    const float* lin_w  = (const float*)d_in[2];   // [D_OUT, D_IN] f32
    const float* lin_b  = (const float*)d_in[3];   // [D_OUT] f32
    const float* weight = (const float*)d_in[4];   // [D_OUT, D_OUT] f32
    float* out = (float*)d_out;                    // [N, D] f32

    char* ws = (char*)d_ws;
    const size_t YB2 = (size_t)N_NODES * D * sizeof(u16);   // 25.6 MB (bf16 y)
    const size_t NB4 = (size_t)N_NODES * sizeof(u32);       // 400 KB
    u16*   y     = (u16*)ws;
    u32*   deg   = (u32*)(ws + YB2);
    u32*   loc   = (u32*)(ws + YB2 + NB4);                  // cursor after fill
    u32*   bsum  = (u32*)(ws + YB2 + 2 * NB4);              // 512 B
    u16*   Mfrag = (u16*)(ws + YB2 + 2 * NB4 + 512);        // 32 KB
    float* b2    = (float*)(ws + YB2 + 2 * NB4 + 512 + 32768);
    int*   csr   = (int*)(ws + YB2 + 2 * NB4 + 512 + 32768 + 512);

    hipMemsetAsync(deg, 0, NB4, stream);   // only deg needs zeroing

    hist_pre_kernel<<<1024, 256, 0, stream>>>(ei, lin_w, lin_b, weight, deg, Mfrag, b2);
    scan_up_kernel<<<SCAN_B, 256, 0, stream>>>(deg, loc, bsum);
    scan_fix_kernel<<<SCAN_B, 256, 0, stream>>>(loc, bsum);
    fill_transform_kernel<<<N_NODES / 32, 256, 0, stream>>>(ei, loc, csr, x, Mfrag, y);
    gather_kernel<<<(N_NODES * 32 + 255) / 256, 256, 0, stream>>>(y, csr, loc, deg, b2, out);
}